// Round 1
// baseline (8521.210 us; speedup 1.0000x reference)
//
#include <hip/hip_runtime.h>

#define HH 300
#define WW 300
#define TS 16
#define CSTEP 4

// ---------------------------------------------------------------------------
// Kernel 1: conv3x3 (CIN -> 64) + BN + ReLU, fp32.
// Block: 256 threads = 16x16 output pixels; each thread accumulates all 64
// output channels in registers. Input tile (18x18 halo) staged in LDS,
// CSTEP channels per barrier. Weights are wave-uniform -> scalar loads.
// ---------------------------------------------------------------------------
template <int CIN>
__global__ __launch_bounds__(256) void conv3_bn_relu_k(
    const float* __restrict__ in,   // [B][CIN][300][300]
    const float* __restrict__ w,    // [64][CIN][3][3]
    const float* __restrict__ gg, const float* __restrict__ bb,
    const float* __restrict__ mm, const float* __restrict__ vv,
    float* __restrict__ out)        // [B][64][300][300]
{
    __shared__ float tile[CSTEP][TS + 2][TS + 2];
    const int tx = threadIdx.x & (TS - 1);
    const int ty = threadIdx.x / TS;
    const int x0 = blockIdx.x * TS, y0 = blockIdx.y * TS;
    const int b = blockIdx.z;
    const int x = x0 + tx, y = y0 + ty;

    float acc[64];
#pragma unroll
    for (int i = 0; i < 64; ++i) acc[i] = 0.f;

    const float* inb = in + (size_t)b * CIN * HH * WW;

    for (int c0 = 0; c0 < CIN; c0 += CSTEP) {
        __syncthreads();
        for (int idx = threadIdx.x; idx < CSTEP * (TS + 2) * (TS + 2); idx += 256) {
            int cc = idx / ((TS + 2) * (TS + 2));
            int r = idx - cc * (TS + 2) * (TS + 2);
            int yy = r / (TS + 2);
            int xx = r - yy * (TS + 2);
            int gy = y0 + yy - 1, gx = x0 + xx - 1;
            float val = 0.f;
            if ((unsigned)gy < (unsigned)HH && (unsigned)gx < (unsigned)WW)
                val = inb[(size_t)(c0 + cc) * (HH * WW) + (size_t)gy * WW + gx];
            tile[cc][yy][xx] = val;
        }
        __syncthreads();
        for (int cc = 0; cc < CSTEP; ++cc) {
            const float i00 = tile[cc][ty][tx],     i01 = tile[cc][ty][tx + 1],     i02 = tile[cc][ty][tx + 2];
            const float i10 = tile[cc][ty + 1][tx], i11 = tile[cc][ty + 1][tx + 1], i12 = tile[cc][ty + 1][tx + 2];
            const float i20 = tile[cc][ty + 2][tx], i21 = tile[cc][ty + 2][tx + 1], i22 = tile[cc][ty + 2][tx + 2];
            const int c = c0 + cc;
#pragma unroll
            for (int oc = 0; oc < 64; ++oc) {
                const float* wp = w + ((size_t)oc * CIN + c) * 9;  // uniform -> s_load
                float a = acc[oc];
                a = fmaf(i00, wp[0], a);
                a = fmaf(i01, wp[1], a);
                a = fmaf(i02, wp[2], a);
                a = fmaf(i10, wp[3], a);
                a = fmaf(i11, wp[4], a);
                a = fmaf(i12, wp[5], a);
                a = fmaf(i20, wp[6], a);
                a = fmaf(i21, wp[7], a);
                a = fmaf(i22, wp[8], a);
                acc[oc] = a;
            }
        }
    }

    if (x < WW && y < HH) {
        float* ob = out + (size_t)b * 64 * HH * WW + (size_t)y * WW + x;
#pragma unroll
        for (int oc = 0; oc < 64; ++oc) {
            float scale = gg[oc] / sqrtf(vv[oc] + 1e-5f);
            float shift = bb[oc] - mm[oc] * scale;
            float r = fmaf(acc[oc], scale, shift);
            ob[(size_t)oc * (HH * WW)] = r > 0.f ? r : 0.f;
        }
    }
}

// ---------------------------------------------------------------------------
// Kernel 2: head = conv3x3(64->64)+BN+ReLU, then fused conv1x1(64->NOUT)+bias
// from registers (mid activation never touches HBM).
// ---------------------------------------------------------------------------
template <int NOUT>
__global__ __launch_bounds__(256) void head_k(
    const float* __restrict__ in,   // shared [B][64][300][300]
    const float* __restrict__ w1,   // [64][64][3][3]
    const float* __restrict__ gg, const float* __restrict__ bb,
    const float* __restrict__ mm, const float* __restrict__ vv,
    const float* __restrict__ w2,   // [NOUT][64]
    const float* __restrict__ b2,   // [NOUT]
    float* __restrict__ out)        // [B][NOUT][300][300]
{
    const int CIN = 64;
    __shared__ float tile[CSTEP][TS + 2][TS + 2];
    const int tx = threadIdx.x & (TS - 1);
    const int ty = threadIdx.x / TS;
    const int x0 = blockIdx.x * TS, y0 = blockIdx.y * TS;
    const int b = blockIdx.z;
    const int x = x0 + tx, y = y0 + ty;

    float acc[64];
#pragma unroll
    for (int i = 0; i < 64; ++i) acc[i] = 0.f;

    const float* inb = in + (size_t)b * CIN * HH * WW;

    for (int c0 = 0; c0 < CIN; c0 += CSTEP) {
        __syncthreads();
        for (int idx = threadIdx.x; idx < CSTEP * (TS + 2) * (TS + 2); idx += 256) {
            int cc = idx / ((TS + 2) * (TS + 2));
            int r = idx - cc * (TS + 2) * (TS + 2);
            int yy = r / (TS + 2);
            int xx = r - yy * (TS + 2);
            int gy = y0 + yy - 1, gx = x0 + xx - 1;
            float val = 0.f;
            if ((unsigned)gy < (unsigned)HH && (unsigned)gx < (unsigned)WW)
                val = inb[(size_t)(c0 + cc) * (HH * WW) + (size_t)gy * WW + gx];
            tile[cc][yy][xx] = val;
        }
        __syncthreads();
        for (int cc = 0; cc < CSTEP; ++cc) {
            const float i00 = tile[cc][ty][tx],     i01 = tile[cc][ty][tx + 1],     i02 = tile[cc][ty][tx + 2];
            const float i10 = tile[cc][ty + 1][tx], i11 = tile[cc][ty + 1][tx + 1], i12 = tile[cc][ty + 1][tx + 2];
            const float i20 = tile[cc][ty + 2][tx], i21 = tile[cc][ty + 2][tx + 1], i22 = tile[cc][ty + 2][tx + 2];
            const int c = c0 + cc;
#pragma unroll
            for (int oc = 0; oc < 64; ++oc) {
                const float* wp = w1 + ((size_t)oc * CIN + c) * 9;  // uniform -> s_load
                float a = acc[oc];
                a = fmaf(i00, wp[0], a);
                a = fmaf(i01, wp[1], a);
                a = fmaf(i02, wp[2], a);
                a = fmaf(i10, wp[3], a);
                a = fmaf(i11, wp[4], a);
                a = fmaf(i12, wp[5], a);
                a = fmaf(i20, wp[6], a);
                a = fmaf(i21, wp[7], a);
                a = fmaf(i22, wp[8], a);
                acc[oc] = a;
            }
        }
    }

    if (x < WW && y < HH) {
        // BN + ReLU in place
#pragma unroll
        for (int oc = 0; oc < 64; ++oc) {
            float scale = gg[oc] / sqrtf(vv[oc] + 1e-5f);
            float shift = bb[oc] - mm[oc] * scale;
            float r = fmaf(acc[oc], scale, shift);
            acc[oc] = r > 0.f ? r : 0.f;
        }
        float* ob = out + (size_t)b * NOUT * HH * WW + (size_t)y * WW + x;
#pragma unroll
        for (int n = 0; n < NOUT; ++n) {
            float s = b2[n];
#pragma unroll
            for (int oc = 0; oc < 64; ++oc)
                s = fmaf(acc[oc], w2[n * 64 + oc], s);
            ob[(size_t)n * (HH * WW)] = s;
        }
    }
}

extern "C" void kernel_launch(void* const* d_in, const int* in_sizes, int n_in,
                              void* d_out, int out_size, void* d_ws, size_t ws_size,
                              hipStream_t stream) {
    const float* bev    = (const float*)d_in[0];
    const float* w_sh   = (const float*)d_in[1];
    const float* g_sh   = (const float*)d_in[2];
    const float* b_sh   = (const float*)d_in[3];
    const float* m_sh   = (const float*)d_in[4];
    const float* v_sh   = (const float*)d_in[5];
    const float* w_hm1  = (const float*)d_in[6];
    const float* g_hm1  = (const float*)d_in[7];
    const float* b_hm1  = (const float*)d_in[8];
    const float* m_hm1  = (const float*)d_in[9];
    const float* v_hm1  = (const float*)d_in[10];
    const float* w_hm2  = (const float*)d_in[11];
    const float* b_hm2  = (const float*)d_in[12];
    const float* w_reg1 = (const float*)d_in[13];
    const float* g_reg1 = (const float*)d_in[14];
    const float* b_reg1 = (const float*)d_in[15];
    const float* m_reg1 = (const float*)d_in[16];
    const float* v_reg1 = (const float*)d_in[17];
    const float* w_reg2 = (const float*)d_in[18];
    const float* b_reg2 = (const float*)d_in[19];

    float* shared_buf = (float*)d_ws;                       // 4*64*300*300 f32 = 92.16 MB
    float* heatmap = (float*)d_out;                         // [4,3,300,300]
    float* box_reg = (float*)d_out + (size_t)4 * 3 * HH * WW;  // [4,8,300,300]

    dim3 grid((WW + TS - 1) / TS, (HH + TS - 1) / TS, 4);
    dim3 block(256, 1, 1);

    conv3_bn_relu_k<256><<<grid, block, 0, stream>>>(
        bev, w_sh, g_sh, b_sh, m_sh, v_sh, shared_buf);

    head_k<3><<<grid, block, 0, stream>>>(
        shared_buf, w_hm1, g_hm1, b_hm1, m_hm1, v_hm1, w_hm2, b_hm2, heatmap);

    head_k<8><<<grid, block, 0, stream>>>(
        shared_buf, w_reg1, g_reg1, b_reg1, m_reg1, v_reg1, w_reg2, b_reg2, box_reg);
}

// Round 2
// 1126.401 us; speedup vs baseline: 7.5650x; 7.5650x over previous
//
#include <hip/hip_runtime.h>

// ---------------------------------------------------------------------------
// CenterPointHead on MI355X — bf16 MFMA implicit-GEMM rewrite.
//
// conv3x3 as 9-tap shifted GEMM: out[oc][pix] += sum_tap W_tap[oc][ic]*in[ic][pix+off]
// A (weights) pre-packed in MFMA A-fragment order, B read from NHWC bf16.
// mfma_f32_16x16x32_bf16: A[m=lane&15][k=quad*8+j], B[k=quad*8+j][n=lane&15],
// D[m=quad*4+reg][n=lane&15]  (m89/m91-verified C/D layout).
// ---------------------------------------------------------------------------

typedef __attribute__((ext_vector_type(8))) short bf16x8;
typedef __attribute__((ext_vector_type(4))) float f32x4;

#define WIMG 300
#define HW 90000

__device__ __forceinline__ unsigned short f2bf(float f) {
    unsigned u = __float_as_uint(f);
    u += 0x7fff + ((u >> 16) & 1);   // round-to-nearest-even
    return (unsigned short)(u >> 16);
}

// ---------------------------------------------------------------------------
// NCHW fp32 -> NHWC bf16 transpose (one batch), LDS-tiled.
// tile = 128 pixels x 32 channels.
// ---------------------------------------------------------------------------
__global__ __launch_bounds__(256) void nchw2nhwc_bf16_k(
    const float* __restrict__ in,          // [256][90000]
    unsigned short* __restrict__ out)      // [90000][256]
{
    __shared__ unsigned short lds[128][33];
    const int p0 = blockIdx.x * 128;
    const int c0 = blockIdx.y * 32;
    const int tid = threadIdx.x;
#pragma unroll
    for (int it = 0; it < 16; ++it) {
        int idx = it * 256 + tid;
        int p = idx & 127, c = idx >> 7;
        float v = 0.f;
        if (p0 + p < HW) v = in[(size_t)(c0 + c) * HW + p0 + p];
        lds[p][c] = f2bf(v);
    }
    __syncthreads();
#pragma unroll
    for (int it = 0; it < 16; ++it) {
        int idx = it * 256 + tid;
        int c = idx & 31, p = idx >> 5;
        if (p0 + p < HW) out[(size_t)(p0 + p) * 256 + c0 + c] = lds[p][c];
    }
}

// ---------------------------------------------------------------------------
// Pack conv3x3 weights [64][CIN][3][3] fp32 -> A-fragment-ordered bf16.
// Layout: apack[mt][kstep][lane][j], k-order = tap*CIN + ic (tap-major).
// oc = mt*16 + (lane&15); k = kstep*32 + (lane>>4)*8 + j.
// ---------------------------------------------------------------------------
__global__ __launch_bounds__(256) void pack_w_k(
    const float* __restrict__ w, unsigned short* __restrict__ apack, int CIN)
{
    const int KST = CIN * 9 / 32;
    const int tot = 4 * KST * 64 * 8;
    int idx = blockIdx.x * 256 + threadIdx.x;
    if (idx >= tot) return;
    int j = idx & 7;
    int lane = (idx >> 3) & 63;
    int rest = idx >> 9;
    int kstep = rest % KST;
    int mt = rest / KST;
    int oc = mt * 16 + (lane & 15);
    int kk = kstep * 32 + (lane >> 4) * 8 + j;
    int tap = kk / CIN, ic = kk % CIN;
    apack[idx] = f2bf(w[((size_t)oc * CIN + ic) * 9 + tap]);
}

// ---------------------------------------------------------------------------
// Fused conv3x3 + BN + ReLU (+ optional conv1x1 head) via MFMA.
// Block = 256 threads (4 waves). Block tile: 64 oc x (2 rows x 64 cols).
// Wave w: all 4 M-tiles x 2 N-tiles (rows 0,1 at cols x0 + 16*w .. +15).
// NOUT == 0: trunk -> BN+ReLU -> NHWC bf16 store.
// NOUT  > 0: head  -> BN+ReLU -> 1x1(+bias) via cross-quad shfl -> NCHW fp32.
// ---------------------------------------------------------------------------
template <int CIN, int NOUT>
__global__ __launch_bounds__(256) void conv3_mfma_k(
    const unsigned short* __restrict__ in_nhwc,  // [300][300][CIN] bf16
    const uint4* __restrict__ apack,             // [4][KST][64] x 16B
    const float* __restrict__ gg, const float* __restrict__ bb,
    const float* __restrict__ mm, const float* __restrict__ vv,
    const float* __restrict__ w2, const float* __restrict__ b2,
    unsigned short* __restrict__ out_nhwc,       // trunk out [300][300][64]
    float* __restrict__ out_f32)                 // head out [NOUT][90000]
{
    constexpr int KST = CIN * 9 / 32;
    constexpr int KSUB = CIN / 32;
    const int wave = threadIdx.x >> 6;
    const int lane = threadIdx.x & 63;
    const int n16 = lane & 15;
    const int quad = lane >> 4;
    const int x0 = blockIdx.x * 64;
    const int y0 = blockIdx.y * 2;
    const int xg = x0 + wave * 16 + n16;

    f32x4 acc[4][2];
#pragma unroll
    for (int mt = 0; mt < 4; ++mt)
#pragma unroll
        for (int r = 0; r < 2; ++r)
            acc[mt][r] = (f32x4){0.f, 0.f, 0.f, 0.f};

    union U16 { uint4 u; bf16x8 h; };

    for (int tap = 0; tap < 9; ++tap) {
        const int dy = tap / 3 - 1, dx = tap % 3 - 1;
        const int xs = xg + dx;
        const bool xok = (unsigned)xs < (unsigned)WIMG;
        const int ys0 = y0 + dy;
        const bool v0 = xok && ((unsigned)ys0 < (unsigned)WIMG);
        const bool v1 = xok && ((unsigned)(ys0 + 1) < (unsigned)WIMG);
        const unsigned short* bp0 = in_nhwc + ((size_t)ys0 * WIMG + xs) * CIN + quad * 8;
        const unsigned short* bp1 = bp0 + (size_t)WIMG * CIN;
        const uint4* ap = apack + (size_t)tap * KSUB * 64 + lane;
#pragma unroll
        for (int ks = 0; ks < KSUB; ++ks) {
            const uint4 z = {0u, 0u, 0u, 0u};
            U16 b0, b1;
            b0.u = v0 ? *(const uint4*)(bp0 + ks * 32) : z;
            b1.u = v1 ? *(const uint4*)(bp1 + ks * 32) : z;
#pragma unroll
            for (int mt = 0; mt < 4; ++mt) {
                U16 a;
                a.u = ap[(size_t)(mt * KST + ks) * 64];
                acc[mt][0] = __builtin_amdgcn_mfma_f32_16x16x32_bf16(a.h, b0.h, acc[mt][0], 0, 0, 0);
                acc[mt][1] = __builtin_amdgcn_mfma_f32_16x16x32_bf16(a.h, b1.h, acc[mt][1], 0, 0, 0);
            }
        }
    }

    // BN scale/shift for this lane's 16 channels (m = mt*16 + quad*4 + j)
    float scl[4][4], sft[4][4];
#pragma unroll
    for (int mt = 0; mt < 4; ++mt)
#pragma unroll
        for (int j = 0; j < 4; ++j) {
            int c = mt * 16 + quad * 4 + j;
            float s = gg[c] / sqrtf(vv[c] + 1e-5f);
            scl[mt][j] = s;
            sft[mt][j] = bb[c] - mm[c] * s;
        }

    if (NOUT == 0) {
        if (xg < WIMG) {
#pragma unroll
            for (int r = 0; r < 2; ++r) {
                unsigned short* op = out_nhwc + ((size_t)(y0 + r) * WIMG + xg) * 64 + quad * 4;
#pragma unroll
                for (int mt = 0; mt < 4; ++mt) {
                    union { unsigned short s[4]; uint2 u; } pk;
#pragma unroll
                    for (int j = 0; j < 4; ++j) {
                        float t = acc[mt][r][j] * scl[mt][j] + sft[mt][j];
                        pk.s[j] = f2bf(t > 0.f ? t : 0.f);
                    }
                    *(uint2*)(op + mt * 16) = pk.u;
                }
            }
        }
    } else {
        float mid[2][4][4];
#pragma unroll
        for (int r = 0; r < 2; ++r)
#pragma unroll
            for (int mt = 0; mt < 4; ++mt)
#pragma unroll
                for (int j = 0; j < 4; ++j) {
                    float t = acc[mt][r][j] * scl[mt][j] + sft[mt][j];
                    mid[r][mt][j] = t > 0.f ? t : 0.f;
                }
        const bool xvalid = xg < WIMG;
#pragma unroll
        for (int no = 0; no < NOUT; ++no) {
            float wv[4][4];
#pragma unroll
            for (int mt = 0; mt < 4; ++mt)
#pragma unroll
                for (int j = 0; j < 4; ++j)
                    wv[mt][j] = w2[no * 64 + mt * 16 + quad * 4 + j];
#pragma unroll
            for (int r = 0; r < 2; ++r) {
                float s = 0.f;
#pragma unroll
                for (int mt = 0; mt < 4; ++mt)
#pragma unroll
                    for (int j = 0; j < 4; ++j)
                        s += mid[r][mt][j] * wv[mt][j];
                s += __shfl_xor(s, 16);
                s += __shfl_xor(s, 32);
                if (((no & 3) == quad) && xvalid)
                    out_f32[(size_t)no * HW + (size_t)(y0 + r) * WIMG + xg] = s + b2[no];
            }
        }
    }
}

// ---------------------------------------------------------------------------
extern "C" void kernel_launch(void* const* d_in, const int* in_sizes, int n_in,
                              void* d_out, int out_size, void* d_ws, size_t ws_size,
                              hipStream_t stream) {
    const float* bev    = (const float*)d_in[0];
    const float* w_sh   = (const float*)d_in[1];
    const float* g_sh   = (const float*)d_in[2];
    const float* b_sh   = (const float*)d_in[3];
    const float* m_sh   = (const float*)d_in[4];
    const float* v_sh   = (const float*)d_in[5];
    const float* w_hm1  = (const float*)d_in[6];
    const float* g_hm1  = (const float*)d_in[7];
    const float* b_hm1  = (const float*)d_in[8];
    const float* m_hm1  = (const float*)d_in[9];
    const float* v_hm1  = (const float*)d_in[10];
    const float* w_hm2  = (const float*)d_in[11];
    const float* b_hm2  = (const float*)d_in[12];
    const float* w_reg1 = (const float*)d_in[13];
    const float* g_reg1 = (const float*)d_in[14];
    const float* b_reg1 = (const float*)d_in[15];
    const float* m_reg1 = (const float*)d_in[16];
    const float* v_reg1 = (const float*)d_in[17];
    const float* w_reg2 = (const float*)d_in[18];
    const float* b_reg2 = (const float*)d_in[19];

    // workspace layout (58.04 MB total; 92.16 MB proven available in R0)
    char* ws = (char*)d_ws;
    unsigned short* inbuf     = (unsigned short*)(ws);             // 46,080,000 B
    unsigned short* sharedbuf = (unsigned short*)(ws + 46080000);  // 11,520,000 B
    unsigned short* apk1      = (unsigned short*)(ws + 57600000);  //    294,912 B
    unsigned short* apkh      = (unsigned short*)(ws + 57894912);  //     73,728 B
    unsigned short* apkr      = (unsigned short*)(ws + 57968640);  //     73,728 B

    float* heatmap = (float*)d_out;                       // [4][3][90000]
    float* box_reg = heatmap + (size_t)4 * 3 * HW;        // [4][8][90000]

    pack_w_k<<<dim3(576), 256, 0, stream>>>(w_sh, apk1, 256);
    pack_w_k<<<dim3(144), 256, 0, stream>>>(w_hm1, apkh, 64);
    pack_w_k<<<dim3(144), 256, 0, stream>>>(w_reg1, apkr, 64);

    const dim3 cgrid(5, 150, 1);   // 5*64 >= 300 cols, 150*2 = 300 rows
    for (int b = 0; b < 4; ++b) {
        nchw2nhwc_bf16_k<<<dim3(704, 8), 256, 0, stream>>>(
            bev + (size_t)b * 256 * HW, inbuf);
        conv3_mfma_k<256, 0><<<cgrid, 256, 0, stream>>>(
            inbuf, (const uint4*)apk1, g_sh, b_sh, m_sh, v_sh,
            nullptr, nullptr, sharedbuf, nullptr);
        conv3_mfma_k<64, 3><<<cgrid, 256, 0, stream>>>(
            sharedbuf, (const uint4*)apkh, g_hm1, b_hm1, m_hm1, v_hm1,
            w_hm2, b_hm2, nullptr, heatmap + (size_t)b * 3 * HW);
        conv3_mfma_k<64, 8><<<cgrid, 256, 0, stream>>>(
            sharedbuf, (const uint4*)apkr, g_reg1, b_reg1, m_reg1, v_reg1,
            w_reg2, b_reg2, nullptr, box_reg + (size_t)b * 8 * HW);
    }
}

// Round 3
// 1056.524 us; speedup vs baseline: 8.0653x; 1.0661x over previous
//
#include <hip/hip_runtime.h>

// ---------------------------------------------------------------------------
// CenterPointHead on MI355X — bf16 MFMA implicit-GEMM, batched grids (R3).
//
// conv3x3 as 9-tap shifted GEMM. A (weights) pre-packed per-tap in MFMA
// A-fragment order [tap][ks][mt][lane](16B); B read from NHWC bf16 global.
// mfma_f32_16x16x32_bf16: A[m=lane&15][k=quad*8+j], B[k=quad*8+j][n=lane&15],
// D[m=quad*4+reg][n=lane&15]  (m89/m91-verified C/D layout).
// Wave tile: 64 oc x 64 px (4 M-tiles x 4 N-tiles, 64 acc regs).
// Block: 4 waves = 4 rows x 64 cols. Grid (5, 75, B).
// ---------------------------------------------------------------------------

typedef __attribute__((ext_vector_type(8))) short bf16x8;
typedef __attribute__((ext_vector_type(4))) float f32x4;

#define WIMG 300
#define HW 90000

__device__ __forceinline__ unsigned short f2bf(float f) {
    unsigned u = __float_as_uint(f);
    u += 0x7fff + ((u >> 16) & 1);   // round-to-nearest-even
    return (unsigned short)(u >> 16);
}

// ---------------------------------------------------------------------------
// NCHW fp32 -> NHWC bf16 transpose, all batches (blockIdx.z).
// ---------------------------------------------------------------------------
__global__ __launch_bounds__(256) void nchw2nhwc_bf16_k(
    const float* __restrict__ in_all,          // [B][256][90000]
    unsigned short* __restrict__ out_all)      // [B][90000][256]
{
    __shared__ unsigned short lds[128][33];
    const int p0 = blockIdx.x * 128;
    const int c0 = blockIdx.y * 32;
    const int b = blockIdx.z;
    const float* in = in_all + (size_t)b * 256 * HW;
    unsigned short* out = out_all + (size_t)b * HW * 256;
    const int tid = threadIdx.x;
#pragma unroll
    for (int it = 0; it < 16; ++it) {
        int idx = it * 256 + tid;
        int p = idx & 127, c = idx >> 7;
        float v = 0.f;
        if (p0 + p < HW) v = in[(size_t)(c0 + c) * HW + p0 + p];
        lds[p][c] = f2bf(v);
    }
    __syncthreads();
#pragma unroll
    for (int it = 0; it < 16; ++it) {
        int idx = it * 256 + tid;
        int c = idx & 31, p = idx >> 5;
        if (p0 + p < HW) out[(size_t)(p0 + p) * 256 + c0 + c] = lds[p][c];
    }
}

// ---------------------------------------------------------------------------
// Pack conv3x3 weights [64][CIN][3][3] fp32 -> A-frag bf16, layout
// [tap][ks][mt][lane][j]:  oc = mt*16+(lane&15), ic = ks*32+(lane>>4)*8+j.
// ---------------------------------------------------------------------------
__global__ __launch_bounds__(256) void pack_w_k(
    const float* __restrict__ w, unsigned short* __restrict__ apack, int CIN)
{
    const int KSUB = CIN / 32;
    const int tot = 9 * KSUB * 4 * 64 * 8;
    int idx = blockIdx.x * 256 + threadIdx.x;
    if (idx >= tot) return;
    int j = idx & 7;
    int lane = (idx >> 3) & 63;
    int rest = idx >> 9;
    int mt = rest & 3;
    int rest2 = rest >> 2;
    int ks = rest2 % KSUB;
    int tap = rest2 / KSUB;
    int oc = mt * 16 + (lane & 15);
    int ic = ks * 32 + (lane >> 4) * 8 + j;
    apack[idx] = f2bf(w[((size_t)oc * CIN + ic) * 9 + tap]);
}

// ---------------------------------------------------------------------------
// Fused conv3x3 + BN + ReLU (+ optional conv1x1 head) via MFMA, batched.
// NOUT == 0: trunk -> BN+ReLU -> NHWC bf16 store.
// NOUT  > 0: head  -> BN+ReLU -> 1x1(+bias) cross-quad shfl -> NCHW fp32.
// ---------------------------------------------------------------------------
template <int CIN, int NOUT>
__global__ __launch_bounds__(256) void conv3_mfma_k(
    const unsigned short* __restrict__ in_all,   // [B][300][300][CIN] bf16
    const uint4* __restrict__ apack,             // [9][KSUB][4][64] x 16B
    const float* __restrict__ gg, const float* __restrict__ bb,
    const float* __restrict__ mm, const float* __restrict__ vv,
    const float* __restrict__ w2, const float* __restrict__ b2,
    unsigned short* __restrict__ out_nhwc_all,   // [B][300][300][64]
    float* __restrict__ out_f32_all)             // [B][NOUT][90000]
{
    constexpr int KSUB = CIN / 32;
    const int wave = threadIdx.x >> 6;
    const int lane = threadIdx.x & 63;
    const int n16 = lane & 15;
    const int quad = lane >> 4;
    const int x0 = blockIdx.x * 64;
    const int y = blockIdx.y * 4 + wave;
    const int b = blockIdx.z;
    const unsigned short* inb = in_all + (size_t)b * HW * CIN;

    f32x4 acc[4][4];
#pragma unroll
    for (int mt = 0; mt < 4; ++mt)
#pragma unroll
        for (int nt = 0; nt < 4; ++nt)
            acc[mt][nt] = (f32x4){0.f, 0.f, 0.f, 0.f};

    union U16 { uint4 u; bf16x8 h; };
    const uint4 z4 = {0u, 0u, 0u, 0u};

#pragma unroll
    for (int tap = 0; tap < 9; ++tap) {
        const int dy = tap / 3 - 1, dx = tap % 3 - 1;
        const int ys = y + dy;
        const bool yok = (unsigned)ys < (unsigned)WIMG;
        const unsigned short* bp[4];
        bool vld[4];
#pragma unroll
        for (int nt = 0; nt < 4; ++nt) {
            int xs = x0 + nt * 16 + n16 + dx;
            vld[nt] = yok && ((unsigned)xs < (unsigned)WIMG);
            bp[nt] = inb + ((size_t)ys * WIMG + xs) * CIN + quad * 8;
        }
#pragma unroll
        for (int ks = 0; ks < KSUB; ++ks) {
            U16 bf[4];
#pragma unroll
            for (int nt = 0; nt < 4; ++nt)
                bf[nt].u = vld[nt] ? *(const uint4*)(bp[nt] + ks * 32) : z4;
#pragma unroll
            for (int mt = 0; mt < 4; ++mt) {
                U16 a;
                a.u = apack[(size_t)(((tap * KSUB + ks) * 4 + mt) * 64) + lane];
#pragma unroll
                for (int nt = 0; nt < 4; ++nt)
                    acc[mt][nt] = __builtin_amdgcn_mfma_f32_16x16x32_bf16(a.h, bf[nt].h, acc[mt][nt], 0, 0, 0);
            }
        }
    }

    // BN scale/shift for this lane's 16 channels (c = mt*16 + quad*4 + j)
    float scl[4][4], sft[4][4];
#pragma unroll
    for (int mt = 0; mt < 4; ++mt)
#pragma unroll
        for (int j = 0; j < 4; ++j) {
            int c = mt * 16 + quad * 4 + j;
            float s = gg[c] / sqrtf(vv[c] + 1e-5f);
            scl[mt][j] = s;
            sft[mt][j] = bb[c] - mm[c] * s;
        }

    if (NOUT == 0) {
        unsigned short* outb = out_nhwc_all + (size_t)b * HW * 64;
#pragma unroll
        for (int nt = 0; nt < 4; ++nt) {
            int xg = x0 + nt * 16 + n16;
            if (xg < WIMG) {
                unsigned short* op = outb + ((size_t)y * WIMG + xg) * 64 + quad * 4;
#pragma unroll
                for (int mt = 0; mt < 4; ++mt) {
                    union { unsigned short s[4]; uint2 u; } pk;
#pragma unroll
                    for (int j = 0; j < 4; ++j) {
                        float t = acc[mt][nt][j] * scl[mt][j] + sft[mt][j];
                        pk.s[j] = f2bf(t > 0.f ? t : 0.f);
                    }
                    *(uint2*)(op + mt * 16) = pk.u;
                }
            }
        }
    } else {
        // BN+ReLU in place
#pragma unroll
        for (int mt = 0; mt < 4; ++mt)
#pragma unroll
            for (int nt = 0; nt < 4; ++nt)
#pragma unroll
                for (int j = 0; j < 4; ++j) {
                    float t = acc[mt][nt][j] * scl[mt][j] + sft[mt][j];
                    acc[mt][nt][j] = t > 0.f ? t : 0.f;
                }
        float* outb = out_f32_all + (size_t)b * NOUT * HW;
#pragma unroll
        for (int no = 0; no < NOUT; ++no) {
            float wv[4][4];
#pragma unroll
            for (int mt = 0; mt < 4; ++mt)
#pragma unroll
                for (int j = 0; j < 4; ++j)
                    wv[mt][j] = w2[no * 64 + mt * 16 + quad * 4 + j];
#pragma unroll
            for (int nt = 0; nt < 4; ++nt) {
                float s = 0.f;
#pragma unroll
                for (int mt = 0; mt < 4; ++mt)
#pragma unroll
                    for (int j = 0; j < 4; ++j)
                        s += acc[mt][nt][j] * wv[mt][j];
                s += __shfl_xor(s, 16);
                s += __shfl_xor(s, 32);
                int xg = x0 + nt * 16 + n16;
                if (((no & 3) == quad) && xg < WIMG)
                    outb[(size_t)no * HW + (size_t)y * WIMG + xg] = s + b2[no];
            }
        }
    }
}

// ---------------------------------------------------------------------------
extern "C" void kernel_launch(void* const* d_in, const int* in_sizes, int n_in,
                              void* d_out, int out_size, void* d_ws, size_t ws_size,
                              hipStream_t stream) {
    const float* bev    = (const float*)d_in[0];
    const float* w_sh   = (const float*)d_in[1];
    const float* g_sh   = (const float*)d_in[2];
    const float* b_sh   = (const float*)d_in[3];
    const float* m_sh   = (const float*)d_in[4];
    const float* v_sh   = (const float*)d_in[5];
    const float* w_hm1  = (const float*)d_in[6];
    const float* g_hm1  = (const float*)d_in[7];
    const float* b_hm1  = (const float*)d_in[8];
    const float* m_hm1  = (const float*)d_in[9];
    const float* v_hm1  = (const float*)d_in[10];
    const float* w_hm2  = (const float*)d_in[11];
    const float* b_hm2  = (const float*)d_in[12];
    const float* w_reg1 = (const float*)d_in[13];
    const float* g_reg1 = (const float*)d_in[14];
    const float* b_reg1 = (const float*)d_in[15];
    const float* m_reg1 = (const float*)d_in[16];
    const float* v_reg1 = (const float*)d_in[17];
    const float* w_reg2 = (const float*)d_in[18];
    const float* b_reg2 = (const float*)d_in[19];

    // workspace layout (~231 MB; d_ws is ~1.44 GB per fill-kernel WRITE_SIZE)
    char* ws = (char*)d_ws;
    unsigned short* inbuf     = (unsigned short*)(ws);              // 184,320,000 B
    unsigned short* sharedbuf = (unsigned short*)(ws + 184320000);  //  46,080,000 B
    unsigned short* apk1      = (unsigned short*)(ws + 230400000);  //     294,912 B
    unsigned short* apkh      = (unsigned short*)(ws + 230694912);  //      73,728 B
    unsigned short* apkr      = (unsigned short*)(ws + 230768640);  //      73,728 B

    float* heatmap = (float*)d_out;                       // [4][3][90000]
    float* box_reg = heatmap + (size_t)4 * 3 * HW;        // [4][8][90000]

    pack_w_k<<<dim3(576), 256, 0, stream>>>(w_sh, apk1, 256);
    pack_w_k<<<dim3(144), 256, 0, stream>>>(w_hm1, apkh, 64);
    pack_w_k<<<dim3(144), 256, 0, stream>>>(w_reg1, apkr, 64);

    nchw2nhwc_bf16_k<<<dim3(704, 8, 4), 256, 0, stream>>>(bev, inbuf);

    const dim3 cgrid(5, 75, 4);   // 5*64 >= 300 cols, 75*4 = 300 rows, 4 batches
    conv3_mfma_k<256, 0><<<cgrid, 256, 0, stream>>>(
        inbuf, (const uint4*)apk1, g_sh, b_sh, m_sh, v_sh,
        nullptr, nullptr, sharedbuf, nullptr);
    conv3_mfma_k<64, 3><<<cgrid, 256, 0, stream>>>(
        sharedbuf, (const uint4*)apkh, g_hm1, b_hm1, m_hm1, v_hm1,
        w_hm2, b_hm2, nullptr, heatmap);
    conv3_mfma_k<64, 8><<<cgrid, 256, 0, stream>>>(
        sharedbuf, (const uint4*)apkr, g_reg1, b_reg1, m_reg1, v_reg1,
        w_reg2, b_reg2, nullptr, box_reg);
}